// Round 13
// baseline (297.248 us; speedup 1.0000x reference)
//
#include <hip/hip_runtime.h>

#define NN 50000
#define NE 800000
#define LN_EPS 1e-5f

#define BSHIFT 9                         // 512 cols per bucket
#define NBUCK 98                         // ceil(50000 / 512)
#define BCAP 10240                       // mean 8163 + ~23 sigma
#define CHUNK_E 8192                     // edges per pass-A block
#define NBLK_A ((NE + CHUNK_E - 1) / CHUNK_E)   // 98

using bf16x8 = __attribute__((ext_vector_type(8))) short;  // 8 bf16 (4 VGPRs)
using f32x4  = __attribute__((ext_vector_type(4))) float;  // MFMA C/D

__device__ __forceinline__ float b2f(unsigned short u) {
    union { unsigned int i; float f; } c;
    c.i = ((unsigned int)u) << 16;
    return c.f;
}
__device__ __forceinline__ unsigned short f2b(float f) {  // RNE
    union { float f; unsigned int i; } c;
    c.f = f;
    const unsigned int i = c.i;
    return (unsigned short)((i + 0x7FFFu + ((i >> 16) & 1u)) >> 16);
}

// async global->LDS copy of ITERS*4KB (256 threads = 4 waves, 16B/lane/iter).
template <int ITERS>
__device__ __forceinline__ void stage_async(const short* __restrict__ g,
                                            short* __restrict__ l) {
    const int lane = threadIdx.x & 63;
    const int wv = threadIdx.x >> 6;
#pragma unroll
    for (int i = 0; i < ITERS; ++i) {
        const int u = i * 256 + wv * 64;
        __builtin_amdgcn_global_load_lds(
            (const __attribute__((address_space(1))) void*)(g + (size_t)(u + lane) * 8),
            (__attribute__((address_space(3))) void*)(l + (size_t)u * 8),
            16, 0, 0);
    }
}

// ---------------------------------------------------------------------------
// prep: fused f32->bf16 convert of x  +  3 weight packs (round-11 proven).
// Wp[(((nt*KB)+kb)*64 + lane)*8 + j] = W[32*kb + 8*(lane>>4) + j][16*nt + (lane&15)]
// ---------------------------------------------------------------------------
template <int K>
__device__ __forceinline__ void pack_body(const float* __restrict__ W,
                                          short* __restrict__ Wp, int i) {
    constexpr int KB = K / 32;
    const int j = i & 7;
    const int l = (i >> 3) & 63;
    const int t = i >> 9;
    const int kb = t % KB;
    const int nt = t / KB;
    const int k = 32 * kb + 8 * (l >> 4) + j;
    const int n = 16 * nt + (l & 15);
    Wp[i] = (short)f2b(W[(size_t)k * 256 + n]);
}

__global__ __launch_bounds__(256) void prep_k(
    const float* __restrict__ x, const float* __restrict__ W1,
    const float* __restrict__ W2, const float* __restrict__ pW,
    short* __restrict__ xb, short* __restrict__ Wp1,
    short* __restrict__ Wp2, short* __restrict__ Wpp) {
    const int b = blockIdx.x;
    if (b < 6250) {                                   // cvt: NN*128/4 elems
        const int i = b * 256 + threadIdx.x;
        const float4 v = ((const float4*)x)[i];
        ushort4 o;
        o.x = f2b(v.x); o.y = f2b(v.y); o.z = f2b(v.z); o.w = f2b(v.w);
        ((ushort4*)xb)[i] = o;
    } else if (b < 6250 + 128) {
        pack_body<128>(W1, Wp1, (b - 6250) * 256 + threadIdx.x);
    } else if (b < 6250 + 384) {
        pack_body<256>(W2, Wp2, (b - 6378) * 256 + threadIdx.x);
    } else {
        pack_body<128>(pW, Wpp, (b - 6634) * 256 + threadIdx.x);
    }
}

// ---------------------------------------------------------------------------
// CSR build: count -> hierarchical scan (dinv fused) -> bucketed fill
// ---------------------------------------------------------------------------
__global__ __launch_bounds__(256) void count_k(const int* __restrict__ col,
                                               int* __restrict__ rowptr) {
    const int e = blockIdx.x * 256 + threadIdx.x;
    if (e < NE) atomicAdd(&rowptr[col[e] + 1], 1);
}

__global__ __launch_bounds__(256) void block_sum_k(const int* __restrict__ p,
                                                   int* __restrict__ psum, int n) {
    __shared__ int sh[256];
    const int t = threadIdx.x;
    const int i = blockIdx.x * 256 + t;
    sh[t] = (i < n) ? p[i] : 0;
    __syncthreads();
#pragma unroll
    for (int off = 128; off > 0; off >>= 1) {
        if (t < off) sh[t] += sh[t + off];
        __syncthreads();
    }
    if (t == 0) psum[blockIdx.x] = sh[0];
}

// inclusive scan + carry; emits dinv from pre-scan values (deg of node i-1).
__global__ __launch_bounds__(256) void scan_apply_k(int* __restrict__ p,
                                                    const int* __restrict__ psum,
                                                    float* __restrict__ dinv,
                                                    int n, int nblk) {
    __shared__ int sh[256];
    const int t = threadIdx.x;
    const int b = blockIdx.x;
    const int i = b * 256 + t;
    sh[t] = (t < b && t < nblk) ? psum[t] : 0;
    __syncthreads();
#pragma unroll
    for (int off = 128; off > 0; off >>= 1) {
        if (t < off) sh[t] += sh[t + off];
        __syncthreads();
    }
    const int carry = sh[0];
    __syncthreads();
    const int raw = (i < n) ? p[i] : 0;
    if (i >= 1 && i < n) dinv[i - 1] = rsqrtf((float)raw + 1.0f);
    sh[t] = raw;
    __syncthreads();
#pragma unroll
    for (int off = 1; off < 256; off <<= 1) {
        const int u = (t >= off) ? sh[t - off] : 0;
        __syncthreads();
        sh[t] += u;
        __syncthreads();
    }
    if (i < n) p[i] = sh[t] + carry;
}

// ---------------------------------------------------------------------------
// Pass A: bin 8192 edges/block by col>>9 through LDS; write each bucket's
// run COALESCED into its global bucket region (packed {col:16, src:16}).
// Replaces fill's random grid-wide 8B scatter (63us: 52.9MB partial-line
// write-back at 840GB/s, cross-XCD lines can't merge) with dense writes.
// ---------------------------------------------------------------------------
__global__ __launch_bounds__(256) void bucketA_k(const int* __restrict__ row,
                                                 const int* __restrict__ col,
                                                 int* __restrict__ gcnt,
                                                 unsigned int* __restrict__ gbuck) {
    __shared__ unsigned int stage[CHUNK_E];  // 32 KB, grouped by bucket
    __shared__ int cnt[NBUCK];
    __shared__ int bnd[NBUCK + 1];
    __shared__ int boff[NBUCK];
    __shared__ int gbase[NBUCK];
    const int t = threadIdx.x;
    const int e0 = blockIdx.x * CHUNK_E;
    const int n = min(CHUNK_E, NE - e0);

    for (int i = t; i < NBUCK; i += 256) cnt[i] = 0;
    __syncthreads();
    for (int i = t; i < n; i += 256)
        atomicAdd(&cnt[col[e0 + i] >> BSHIFT], 1);
    __syncthreads();
    if (t == 0) {
        int s = 0;
        for (int b = 0; b < NBUCK; ++b) {
            bnd[b] = s;
            boff[b] = s;
            s += cnt[b];
        }
        bnd[NBUCK] = s;
    }
    __syncthreads();
    for (int b = t; b < NBUCK; b += 256)
        gbase[b] = atomicAdd(&gcnt[b], cnt[b]);
    for (int i = t; i < n; i += 256) {
        const int c = col[e0 + i];
        const int s = row[e0 + i];
        const int p = atomicAdd(&boff[c >> BSHIFT], 1);
        stage[p] = ((unsigned int)c << 16) | (unsigned int)s;  // both < 65536
    }
    __syncthreads();
    for (int i = t; i < n; i += 256) {
        int lo = 0, hi = NBUCK;              // largest b with bnd[b] <= i
        while (hi - lo > 1) {
            const int mid = (lo + hi) >> 1;
            if (bnd[mid] <= i) lo = mid; else hi = mid;
        }
        const int off = gbase[lo] + (i - bnd[lo]);
        gbuck[(size_t)lo * BCAP + min(off, BCAP - 1)] = stage[i];
    }
}

// ---------------------------------------------------------------------------
// Pass B: one block per bucket. All pairs-writes for a bucket fall in one
// contiguous ~65KB window written by ONE block (one XCD) -> L2 merges lines.
// ---------------------------------------------------------------------------
__global__ __launch_bounds__(256) void bucketB_k(const unsigned int* __restrict__ gbuck,
                                                 const int* __restrict__ gcnt,
                                                 const float* __restrict__ dinv,
                                                 int* __restrict__ rowptr,
                                                 int2* __restrict__ pairs) {
    const int b = blockIdx.x;
    const int n = min(gcnt[b], BCAP);
    const unsigned int* src = gbuck + (size_t)b * BCAP;
    int i = threadIdx.x;
    for (; i + 768 < n; i += 1024) {         // 4 independent chains in flight
        const unsigned int u0 = src[i];
        const unsigned int u1 = src[i + 256];
        const unsigned int u2 = src[i + 512];
        const unsigned int u3 = src[i + 768];
        int2 a, bb, c, d;
        a.x = (int)(u0 & 0xffffu);  a.y = __float_as_int(dinv[a.x]);
        bb.x = (int)(u1 & 0xffffu); bb.y = __float_as_int(dinv[bb.x]);
        c.x = (int)(u2 & 0xffffu);  c.y = __float_as_int(dinv[c.x]);
        d.x = (int)(u3 & 0xffffu);  d.y = __float_as_int(dinv[d.x]);
        const int p0 = atomicAdd(&rowptr[u0 >> 16], 1);
        const int p1 = atomicAdd(&rowptr[u1 >> 16], 1);
        const int p2 = atomicAdd(&rowptr[u2 >> 16], 1);
        const int p3 = atomicAdd(&rowptr[u3 >> 16], 1);
        pairs[p0] = a;
        pairs[p1] = bb;
        pairs[p2] = c;
        pairs[p3] = d;
    }
    for (; i < n; i += 256) {
        const unsigned int u = src[i];
        int2 pr;
        pr.x = (int)(u & 0xffffu);
        pr.y = __float_as_int(dinv[pr.x]);
        pairs[atomicAdd(&rowptr[u >> 16], 1)] = pr;
    }
}

// ---------------------------------------------------------------------------
// gather1: agg over 128-ch bf16 rows (x). Wave per dst node; lane owns 2 ch.
// ---------------------------------------------------------------------------
__global__ __launch_bounds__(256) void gather1_k(const short* __restrict__ X,
                                                 const int* __restrict__ endptr,
                                                 const int2* __restrict__ pairs,
                                                 const float* __restrict__ dinv,
                                                 short* __restrict__ A1) {
    const int node = blockIdx.x * 4 + (threadIdx.x >> 6);
    const int lane = threadIdx.x & 63;
    if (node >= NN) return;
    const int start = node ? endptr[node - 1] : 0;
    const int end = endptr[node];

    float a0 = 0.f, a1 = 0.f;
    int j = start;
    for (; j + 7 < end; j += 8) {
        int2 p[8];
        ushort2 v[8];
#pragma unroll
        for (int u = 0; u < 8; ++u) p[u] = pairs[j + u];
#pragma unroll
        for (int u = 0; u < 8; ++u)
            v[u] = ((const ushort2*)(X + (size_t)p[u].x * 128))[lane];
#pragma unroll
        for (int u = 0; u < 8; ++u) {
            const float w = __int_as_float(p[u].y);
            a0 += b2f(v[u].x) * w;
            a1 += b2f(v[u].y) * w;
        }
    }
    for (; j < end; ++j) {
        const int2 p0 = pairs[j];
        const float w0 = __int_as_float(p0.y);
        const ushort2 v0 = ((const ushort2*)(X + (size_t)p0.x * 128))[lane];
        a0 += b2f(v0.x) * w0;
        a1 += b2f(v0.y) * w0;
    }
    const float dc = dinv[node];
    const ushort2 h = ((const ushort2*)(X + (size_t)node * 128))[lane];
    a0 = (a0 + b2f(h.x) * dc) * dc;
    a1 = (a1 + b2f(h.y) * dc) * dc;
    ushort2 o;
    o.x = f2b(a0); o.y = f2b(a1);
    ((ushort2*)A1)[(size_t)node * 64 + lane] = o;
}

// ---------------------------------------------------------------------------
// gather2: agg over 256-ch bf16 rows. Wave per dst node; lane owns 4 ch.
// ---------------------------------------------------------------------------
__global__ __launch_bounds__(256) void gather2_k(const short* __restrict__ H,
                                                 const int* __restrict__ endptr,
                                                 const int2* __restrict__ pairs,
                                                 const float* __restrict__ dinv,
                                                 short* __restrict__ agg) {
    const int node = blockIdx.x * 4 + (threadIdx.x >> 6);
    const int lane = threadIdx.x & 63;
    if (node >= NN) return;
    const int start = node ? endptr[node - 1] : 0;
    const int end = endptr[node];

    float a0 = 0.f, a1 = 0.f, a2 = 0.f, a3 = 0.f;
    int j = start;
    for (; j + 7 < end; j += 8) {
        int2 p[8];
        ushort4 v[8];
#pragma unroll
        for (int u = 0; u < 8; ++u) p[u] = pairs[j + u];
#pragma unroll
        for (int u = 0; u < 8; ++u)
            v[u] = ((const ushort4*)(H + (size_t)p[u].x * 256))[lane];
#pragma unroll
        for (int u = 0; u < 8; ++u) {
            const float w = __int_as_float(p[u].y);
            a0 += b2f(v[u].x) * w;
            a1 += b2f(v[u].y) * w;
            a2 += b2f(v[u].z) * w;
            a3 += b2f(v[u].w) * w;
        }
    }
    for (; j < end; ++j) {
        const int2 p0 = pairs[j];
        const float w0 = __int_as_float(p0.y);
        const ushort4 v0 = ((const ushort4*)(H + (size_t)p0.x * 256))[lane];
        a0 += b2f(v0.x) * w0;
        a1 += b2f(v0.y) * w0;
        a2 += b2f(v0.z) * w0;
        a3 += b2f(v0.w) * w0;
    }
    const float dc = dinv[node];
    const ushort4 h = ((const ushort4*)(H + (size_t)node * 256))[lane];
    ushort4 o;
    o.x = f2b((a0 + b2f(h.x) * dc) * dc);
    o.y = f2b((a1 + b2f(h.y) * dc) * dc);
    o.z = f2b((a2 + b2f(h.z) * dc) * dc);
    o.w = f2b((a3 + b2f(h.w) * dc) * dc);
    ((ushort4*)agg)[(size_t)node * 64 + lane] = o;
}

// ---------------------------------------------------------------------------
// Fused GEMM + bias + LayerNorm [+ proj-GEMM residual] + ReLU.
// Round-9/11 proven structure (278us; persistent/512-thr variants regressed:
// r7/8 spill @128 VGPR, r10 1-block/CU latency exposure — do NOT revisit).
// Weights double-buffered via async global_load_lds in 16KB chunks.
// C/D mapping (m89-verified): col = lane&15, row = (lane>>4)*4 + reg.
// ---------------------------------------------------------------------------
template <int K, bool PROJ, bool OUT_BF16>
__global__ __launch_bounds__(256) void gemm_ln_k(
    const short* __restrict__ X, const short* __restrict__ Wp,
    const float* __restrict__ bias, const float* __restrict__ gamma,
    const float* __restrict__ beta, const short* __restrict__ Xp,
    const short* __restrict__ Wpp, const float* __restrict__ pbias,
    void* __restrict__ Yv) {
    constexpr int KB = K / 32;                 // 4 or 8
    constexpr int NTC = 16 / KB;               // nt per 16KB chunk: 4 or 2
    constexpr int NPH = 16 / NTC;              // phases: 4 or 8
    constexpr int CHUNK = 8192;                // shorts per chunk (16 KB)
    __shared__ short lds[2][CHUNK];            // 32 KB total
    const int lane = threadIdx.x & 63;
    const int wv = threadIdx.x >> 6;
    const int row0 = blockIdx.x * 64 + wv * 16;
    const int r = row0 + (lane & 15);
    const int rc = (r < NN) ? r : (NN - 1);
    const int kof = 8 * (lane >> 4);
    const int colbase = lane & 15;

    bf16x8 a[KB];
#pragma unroll
    for (int kb = 0; kb < KB; ++kb)
        a[kb] = *(const bf16x8*)(X + (size_t)rc * K + 32 * kb + kof);
    bf16x8 ap[4];
    if (PROJ) {
#pragma unroll
        for (int kb = 0; kb < 4; ++kb)
            ap[kb] = *(const bf16x8*)(Xp + (size_t)rc * 128 + 32 * kb + kof);
    }

    stage_async<4>(Wp, lds[0]);                // chunk 0 (16 KB)

    f32x4 acc[16];
#pragma unroll
    for (int c = 0; c < NPH; ++c) {
        __syncthreads();                       // chunk c landed (vmcnt drained)
        if (c < NPH - 1)
            stage_async<4>(Wp + (size_t)(c + 1) * CHUNK, lds[(c + 1) & 1]);
        else if (PROJ)
            stage_async<4>(Wpp, lds[(c + 1) & 1]);  // proj chunk 0
        const short* buf = lds[c & 1];
#pragma unroll
        for (int ntl = 0; ntl < NTC; ++ntl) {
            f32x4 cacc = {0.f, 0.f, 0.f, 0.f};
#pragma unroll
            for (int kb = 0; kb < KB; ++kb) {
                const bf16x8 b = ((const bf16x8*)buf)[(ntl * KB + kb) * 64 + lane];
                cacc = __builtin_amdgcn_mfma_f32_16x16x32_bf16(a[kb], b, cacc, 0, 0, 0);
            }
            acc[c * NTC + ntl] = cacc;
        }
    }

    float s[4] = {0.f, 0.f, 0.f, 0.f};
    float q[4] = {0.f, 0.f, 0.f, 0.f};
#pragma unroll
    for (int nt = 0; nt < 16; ++nt) {
        const float bv = bias[nt * 16 + colbase];
#pragma unroll
        for (int rg = 0; rg < 4; ++rg) {
            const float v = acc[nt][rg] + bv;
            acc[nt][rg] = v;
            s[rg] += v;
            q[rg] += v * v;
        }
    }
#pragma unroll
    for (int off = 1; off < 16; off <<= 1) {
#pragma unroll
        for (int rg = 0; rg < 4; ++rg) {
            s[rg] += __shfl_xor(s[rg], off, 64);
            q[rg] += __shfl_xor(q[rg], off, 64);
        }
    }
    float mu[4], rsd[4];
#pragma unroll
    for (int rg = 0; rg < 4; ++rg) {
        mu[rg] = s[rg] * (1.f / 256.f);
        const float var = q[rg] * (1.f / 256.f) - mu[rg] * mu[rg];
        rsd[rg] = rsqrtf(var + LN_EPS);
    }

    const int orow0 = row0 + (lane >> 4) * 4;
    if (PROJ) {
#pragma unroll
        for (int pc = 0; pc < 4; ++pc) {
            __syncthreads();                   // proj chunk pc landed
            if (pc < 3)
                stage_async<4>(Wpp + (size_t)(pc + 1) * 8192, lds[(pc + 1) & 1]);
            const short* buf = lds[pc & 1];
#pragma unroll
            for (int ntl = 0; ntl < 4; ++ntl) {
                const int nt = pc * 4 + ntl;
                f32x4 pid = {0.f, 0.f, 0.f, 0.f};
#pragma unroll
                for (int kb = 0; kb < 4; ++kb) {
                    const bf16x8 b = ((const bf16x8*)buf)[(ntl * 4 + kb) * 64 + lane];
                    pid = __builtin_amdgcn_mfma_f32_16x16x32_bf16(ap[kb], b, pid, 0, 0, 0);
                }
                const int col = nt * 16 + colbase;
                const float g = gamma[col];
                const float be = beta[col];
                const float pbv = pbias[col];
#pragma unroll
                for (int rg = 0; rg < 4; ++rg) {
                    const int orow = orow0 + rg;
                    float v = (acc[nt][rg] - mu[rg]) * rsd[rg] * g + be;
                    v += pid[rg] + pbv;
                    v = fmaxf(v, 0.f);
                    if (orow < NN) {
                        if (OUT_BF16)
                            ((short*)Yv)[(size_t)orow * 256 + col] = (short)f2b(v);
                        else
                            ((float*)Yv)[(size_t)orow * 256 + col] = v;
                    }
                }
            }
        }
    } else {
#pragma unroll
        for (int nt = 0; nt < 16; ++nt) {
            const int col = nt * 16 + colbase;
            const float g = gamma[col];
            const float be = beta[col];
#pragma unroll
            for (int rg = 0; rg < 4; ++rg) {
                const int orow = orow0 + rg;
                float v = (acc[nt][rg] - mu[rg]) * rsd[rg] * g + be;
                v = fmaxf(v, 0.f);
                if (orow < NN) {
                    if (OUT_BF16)
                        ((short*)Yv)[(size_t)orow * 256 + col] = (short)f2b(v);
                    else
                        ((float*)Yv)[(size_t)orow * 256 + col] = v;
                }
            }
        }
    }
}

// ---------------------------------------------------------------------------
extern "C" void kernel_launch(void* const* d_in, const int* in_sizes, int n_in,
                              void* d_out, int out_size, void* d_ws, size_t ws_size,
                              hipStream_t stream) {
    const float* x    = (const float*)d_in[0];
    const int*   eidx = (const int*)d_in[1];
    const float* W1   = (const float*)d_in[2];
    const float* b1   = (const float*)d_in[3];
    const float* W2   = (const float*)d_in[4];
    const float* b2   = (const float*)d_in[5];
    const float* ln1g = (const float*)d_in[6];
    const float* ln1b = (const float*)d_in[7];
    const float* ln2g = (const float*)d_in[8];
    const float* ln2b = (const float*)d_in[9];
    const float* pW   = (const float*)d_in[10];
    const float* pb   = (const float*)d_in[11];

    const int* row = eidx;        // edge_index[0]
    const int* col = eidx + NE;   // edge_index[1]
    float* out = (float*)d_out;

    short* xb     = (short*)d_ws;                    // [NN,128] bf16
    short* A1     = xb + (size_t)NN * 128;           // [NN,128] bf16 (agg of x)
    short* Bb     = A1 + (size_t)NN * 128;           // [NN,256] bf16 (h)
    short* Ag     = Bb + (size_t)NN * 256;           // [NN,256] bf16 (agg of h)
    float* dinv   = (float*)(Ag + (size_t)NN * 256); // [NN]
    int*   rowptr = (int*)(dinv + NN);               // [NN+4]
    int*   gcnt   = rowptr + NN + 4;                 // [128]
    int*   psum   = gcnt + 128;                      // [256]
    int2*  pairs  = (int2*)(psum + 256);             // [NE] (src, w bits)
    unsigned int* gbuck = (unsigned int*)(pairs + NE);  // [NBUCK*BCAP] 4MB
    short* Wp1    = (short*)(gbuck + (size_t)NBUCK * BCAP);  // 128*256
    short* Wp2    = Wp1 + 128 * 256;                 // 256*256
    short* Wpp    = Wp2 + 256 * 256;                 // 128*256

    const int nscan = NN + 1;
    const int nblk = (nscan + 255) / 256;

    // ---- preprocessing: cvt+packs; count; scan (dinv fused); bucketed fill
    hipMemsetAsync(rowptr, 0, (NN + 4 + 128) * sizeof(int), stream);  // +gcnt
    prep_k<<<6762, 256, 0, stream>>>(x, W1, W2, pW, xb, Wp1, Wp2, Wpp);
    count_k<<<(NE + 255) / 256, 256, 0, stream>>>(col, rowptr);
    block_sum_k<<<nblk, 256, 0, stream>>>(rowptr, psum, nscan);
    scan_apply_k<<<nblk, 256, 0, stream>>>(rowptr, psum, dinv, nscan, nblk);
    bucketA_k<<<NBLK_A, 256, 0, stream>>>(row, col, gcnt, gbuck);
    bucketB_k<<<NBUCK, 256, 0, stream>>>(gbuck, gcnt, dinv, rowptr, pairs);
    // rowptr is now endptr

    // ---- layer 1: A1 = agg(xb); Bb = relu(LN(A1@W1 + b1))
    gather1_k<<<(NN + 3) / 4, 256, 0, stream>>>(xb, rowptr, pairs, dinv, A1);
    gemm_ln_k<128, false, true><<<(NN + 63) / 64, 256, 0, stream>>>(
        A1, Wp1, b1, ln1g, ln1b, nullptr, nullptr, nullptr, Bb);

    // ---- layer 2: Ag = agg(Bb); out = relu(LN(Ag@W2 + b2) + xb@projW + pb)
    gather2_k<<<(NN + 3) / 4, 256, 0, stream>>>(Bb, rowptr, pairs, dinv, Ag);
    gemm_ln_k<256, true, false><<<(NN + 63) / 64, 256, 0, stream>>>(
        Ag, Wp2, b2, ln2g, ln2b, xb, Wpp, pb, out);
}

// Round 14
// 276.506 us; speedup vs baseline: 1.0750x; 1.0750x over previous
//
#include <hip/hip_runtime.h>

#define NN 50000
#define NE 800000
#define LN_EPS 1e-5f

using bf16x8 = __attribute__((ext_vector_type(8))) short;  // 8 bf16 (4 VGPRs)
using f32x4  = __attribute__((ext_vector_type(4))) float;  // MFMA C/D

__device__ __forceinline__ float b2f(unsigned short u) {
    union { unsigned int i; float f; } c;
    c.i = ((unsigned int)u) << 16;
    return c.f;
}
__device__ __forceinline__ unsigned short f2b(float f) {  // RNE
    union { float f; unsigned int i; } c;
    c.f = f;
    const unsigned int i = c.i;
    return (unsigned short)((i + 0x7FFFu + ((i >> 16) & 1u)) >> 16);
}

// async global->LDS copy of ITERS*4KB (256 threads = 4 waves, 16B/lane/iter).
// LDS dest is wave-uniform base + lane*16 (global_load_lds semantics).
template <int ITERS>
__device__ __forceinline__ void stage_async(const short* __restrict__ g,
                                            short* __restrict__ l) {
    const int lane = threadIdx.x & 63;
    const int wv = threadIdx.x >> 6;
#pragma unroll
    for (int i = 0; i < ITERS; ++i) {
        const int u = i * 256 + wv * 64;  // 16B-unit index of this wave's segment
        __builtin_amdgcn_global_load_lds(
            (const __attribute__((address_space(1))) void*)(g + (size_t)(u + lane) * 8),
            (__attribute__((address_space(3))) void*)(l + (size_t)u * 8),
            16, 0, 0);
    }
}

// ---------------------------------------------------------------------------
// prep: fused f32->bf16 convert of x  +  3 weight packs (one launch).
// Pack W[K][256] f32 -> bf16 MFMA B-fragment order:
// Wp[(((nt*KB)+kb)*64 + lane)*8 + j] = W[32*kb + 8*(lane>>4) + j][16*nt + (lane&15)]
// ---------------------------------------------------------------------------
template <int K>
__device__ __forceinline__ void pack_body(const float* __restrict__ W,
                                          short* __restrict__ Wp, int i) {
    constexpr int KB = K / 32;
    const int j = i & 7;
    const int l = (i >> 3) & 63;
    const int t = i >> 9;
    const int kb = t % KB;
    const int nt = t / KB;
    const int k = 32 * kb + 8 * (l >> 4) + j;
    const int n = 16 * nt + (l & 15);
    Wp[i] = (short)f2b(W[(size_t)k * 256 + n]);
}

__global__ __launch_bounds__(256) void prep_k(
    const float* __restrict__ x, const float* __restrict__ W1,
    const float* __restrict__ W2, const float* __restrict__ pW,
    short* __restrict__ xb, short* __restrict__ Wp1,
    short* __restrict__ Wp2, short* __restrict__ Wpp) {
    const int b = blockIdx.x;
    if (b < 6250) {                                   // cvt: NN*128/4 elems
        const int i = b * 256 + threadIdx.x;
        const float4 v = ((const float4*)x)[i];
        ushort4 o;
        o.x = f2b(v.x); o.y = f2b(v.y); o.z = f2b(v.z); o.w = f2b(v.w);
        ((ushort4*)xb)[i] = o;
    } else if (b < 6250 + 128) {
        pack_body<128>(W1, Wp1, (b - 6250) * 256 + threadIdx.x);
    } else if (b < 6250 + 384) {
        pack_body<256>(W2, Wp2, (b - 6378) * 256 + threadIdx.x);
    } else {
        pack_body<128>(pW, Wpp, (b - 6634) * 256 + threadIdx.x);
    }
}

// ---------------------------------------------------------------------------
// CSR build: count -> hierarchical scan (dinv fused) -> fill (src,w pairs)
// fill is at its floor: random 8B scatter = partial-line write-back bound
// (r12 4-edge MLP: 63->70us; r13 two-pass bucketing: total +19us — both
// regressed; do not revisit).
// ---------------------------------------------------------------------------
__global__ __launch_bounds__(256) void count_k(const int* __restrict__ col,
                                               int* __restrict__ rowptr) {
    const int e = blockIdx.x * 256 + threadIdx.x;
    if (e < NE) atomicAdd(&rowptr[col[e] + 1], 1);
}

__global__ __launch_bounds__(256) void block_sum_k(const int* __restrict__ p,
                                                   int* __restrict__ psum, int n) {
    __shared__ int sh[256];
    const int t = threadIdx.x;
    const int i = blockIdx.x * 256 + t;
    sh[t] = (i < n) ? p[i] : 0;
    __syncthreads();
#pragma unroll
    for (int off = 128; off > 0; off >>= 1) {
        if (t < off) sh[t] += sh[t + off];
        __syncthreads();
    }
    if (t == 0) psum[blockIdx.x] = sh[0];
}

// inclusive scan + carry; also emits dinv from the pre-scan values:
// pre-scan p[i] = deg(node i-1), so dinv[i-1] = rsqrt(p[i] + 1).
__global__ __launch_bounds__(256) void scan_apply_k(int* __restrict__ p,
                                                    const int* __restrict__ psum,
                                                    float* __restrict__ dinv,
                                                    int n, int nblk) {
    __shared__ int sh[256];
    const int t = threadIdx.x;
    const int b = blockIdx.x;
    const int i = b * 256 + t;
    sh[t] = (t < b && t < nblk) ? psum[t] : 0;
    __syncthreads();
#pragma unroll
    for (int off = 128; off > 0; off >>= 1) {
        if (t < off) sh[t] += sh[t + off];
        __syncthreads();
    }
    const int carry = sh[0];
    __syncthreads();
    const int raw = (i < n) ? p[i] : 0;
    if (i >= 1 && i < n) dinv[i - 1] = rsqrtf((float)raw + 1.0f);
    sh[t] = raw;
    __syncthreads();
#pragma unroll
    for (int off = 1; off < 256; off <<= 1) {
        const int u = (t >= off) ? sh[t - off] : 0;
        __syncthreads();
        sh[t] += u;
        __syncthreads();
    }
    if (i < n) p[i] = sh[t] + carry;
}

// fill: pairs[pos] = {src, bits(dinv[src])}, bucketed by col[e].
__global__ __launch_bounds__(256) void fill_k(const int* __restrict__ row,
                                              const int* __restrict__ col,
                                              const float* __restrict__ dinv,
                                              int* __restrict__ rowptr,
                                              int2* __restrict__ pairs) {
    const int e = blockIdx.x * 256 + threadIdx.x;
    if (e >= NE) return;
    const int rr = row[e];
    const int pos = atomicAdd(&rowptr[col[e]], 1);
    int2 pr;
    pr.x = rr;
    pr.y = __float_as_int(dinv[rr]);
    pairs[pos] = pr;
}

// ---------------------------------------------------------------------------
// gather1: agg over 128-ch bf16 rows (x). Wave per dst node; lane owns 2 ch.
// 8x unrolled (neutral vs 4x — at the random-gather memory floor).
// ---------------------------------------------------------------------------
__global__ __launch_bounds__(256) void gather1_k(const short* __restrict__ X,
                                                 const int* __restrict__ endptr,
                                                 const int2* __restrict__ pairs,
                                                 const float* __restrict__ dinv,
                                                 short* __restrict__ A1) {
    const int node = blockIdx.x * 4 + (threadIdx.x >> 6);
    const int lane = threadIdx.x & 63;
    if (node >= NN) return;
    const int start = node ? endptr[node - 1] : 0;
    const int end = endptr[node];

    float a0 = 0.f, a1 = 0.f;
    int j = start;
    for (; j + 7 < end; j += 8) {
        int2 p[8];
        ushort2 v[8];
#pragma unroll
        for (int u = 0; u < 8; ++u) p[u] = pairs[j + u];
#pragma unroll
        for (int u = 0; u < 8; ++u)
            v[u] = ((const ushort2*)(X + (size_t)p[u].x * 128))[lane];
#pragma unroll
        for (int u = 0; u < 8; ++u) {
            const float w = __int_as_float(p[u].y);
            a0 += b2f(v[u].x) * w;
            a1 += b2f(v[u].y) * w;
        }
    }
    for (; j < end; ++j) {
        const int2 p0 = pairs[j];
        const float w0 = __int_as_float(p0.y);
        const ushort2 v0 = ((const ushort2*)(X + (size_t)p0.x * 128))[lane];
        a0 += b2f(v0.x) * w0;
        a1 += b2f(v0.y) * w0;
    }
    const float dc = dinv[node];
    const ushort2 h = ((const ushort2*)(X + (size_t)node * 128))[lane];
    a0 = (a0 + b2f(h.x) * dc) * dc;
    a1 = (a1 + b2f(h.y) * dc) * dc;
    ushort2 o;
    o.x = f2b(a0); o.y = f2b(a1);
    ((ushort2*)A1)[(size_t)node * 64 + lane] = o;
}

// ---------------------------------------------------------------------------
// gather2: agg over 256-ch bf16 rows. Wave per dst node; lane owns 4 ch.
// ---------------------------------------------------------------------------
__global__ __launch_bounds__(256) void gather2_k(const short* __restrict__ H,
                                                 const int* __restrict__ endptr,
                                                 const int2* __restrict__ pairs,
                                                 const float* __restrict__ dinv,
                                                 short* __restrict__ agg) {
    const int node = blockIdx.x * 4 + (threadIdx.x >> 6);
    const int lane = threadIdx.x & 63;
    if (node >= NN) return;
    const int start = node ? endptr[node - 1] : 0;
    const int end = endptr[node];

    float a0 = 0.f, a1 = 0.f, a2 = 0.f, a3 = 0.f;
    int j = start;
    for (; j + 7 < end; j += 8) {
        int2 p[8];
        ushort4 v[8];
#pragma unroll
        for (int u = 0; u < 8; ++u) p[u] = pairs[j + u];
#pragma unroll
        for (int u = 0; u < 8; ++u)
            v[u] = ((const ushort4*)(H + (size_t)p[u].x * 256))[lane];
#pragma unroll
        for (int u = 0; u < 8; ++u) {
            const float w = __int_as_float(p[u].y);
            a0 += b2f(v[u].x) * w;
            a1 += b2f(v[u].y) * w;
            a2 += b2f(v[u].z) * w;
            a3 += b2f(v[u].w) * w;
        }
    }
    for (; j < end; ++j) {
        const int2 p0 = pairs[j];
        const float w0 = __int_as_float(p0.y);
        const ushort4 v0 = ((const ushort4*)(H + (size_t)p0.x * 256))[lane];
        a0 += b2f(v0.x) * w0;
        a1 += b2f(v0.y) * w0;
        a2 += b2f(v0.z) * w0;
        a3 += b2f(v0.w) * w0;
    }
    const float dc = dinv[node];
    const ushort4 h = ((const ushort4*)(H + (size_t)node * 256))[lane];
    ushort4 o;
    o.x = f2b((a0 + b2f(h.x) * dc) * dc);
    o.y = f2b((a1 + b2f(h.y) * dc) * dc);
    o.z = f2b((a2 + b2f(h.z) * dc) * dc);
    o.w = f2b((a3 + b2f(h.w) * dc) * dc);
    ((ushort4*)agg)[(size_t)node * 64 + lane] = o;
}

// ---------------------------------------------------------------------------
// Fused GEMM + bias + LayerNorm [+ proj-GEMM residual] + ReLU.
// Round-9/11 proven structure (278us twice; persistent/512-thr variants all
// regressed: r7/8 spill @128 VGPR, r10 1-block/CU latency exposure).
// Weights double-buffered via async global_load_lds in 16KB chunks:
//   phase c: barrier (chunk c landed) -> issue chunk c+1 -> compute chunk c.
// C/D mapping (m89-verified): col = lane&15, row = (lane>>4)*4 + reg.
// ---------------------------------------------------------------------------
template <int K, bool PROJ, bool OUT_BF16>
__global__ __launch_bounds__(256) void gemm_ln_k(
    const short* __restrict__ X, const short* __restrict__ Wp,
    const float* __restrict__ bias, const float* __restrict__ gamma,
    const float* __restrict__ beta, const short* __restrict__ Xp,
    const short* __restrict__ Wpp, const float* __restrict__ pbias,
    void* __restrict__ Yv) {
    constexpr int KB = K / 32;                 // 4 or 8
    constexpr int NTC = 16 / KB;               // nt per 16KB chunk: 4 or 2
    constexpr int NPH = 16 / NTC;              // phases: 4 or 8
    constexpr int CHUNK = 8192;                // shorts per chunk (16 KB)
    __shared__ short lds[2][CHUNK];            // 32 KB total
    const int lane = threadIdx.x & 63;
    const int wv = threadIdx.x >> 6;
    const int row0 = blockIdx.x * 64 + wv * 16;
    const int r = row0 + (lane & 15);
    const int rc = (r < NN) ? r : (NN - 1);
    const int kof = 8 * (lane >> 4);
    const int colbase = lane & 15;

    // A-fragment loads first (overlap with chunk0 staging)
    bf16x8 a[KB];
#pragma unroll
    for (int kb = 0; kb < KB; ++kb)
        a[kb] = *(const bf16x8*)(X + (size_t)rc * K + 32 * kb + kof);
    bf16x8 ap[4];
    if (PROJ) {
#pragma unroll
        for (int kb = 0; kb < 4; ++kb)
            ap[kb] = *(const bf16x8*)(Xp + (size_t)rc * 128 + 32 * kb + kof);
    }

    stage_async<4>(Wp, lds[0]);                // chunk 0 (16 KB)

    f32x4 acc[16];
#pragma unroll
    for (int c = 0; c < NPH; ++c) {
        __syncthreads();                       // chunk c landed (vmcnt drained)
        if (c < NPH - 1)
            stage_async<4>(Wp + (size_t)(c + 1) * CHUNK, lds[(c + 1) & 1]);
        else if (PROJ)
            stage_async<4>(Wpp, lds[(c + 1) & 1]);  // proj chunk 0
        const short* buf = lds[c & 1];
#pragma unroll
        for (int ntl = 0; ntl < NTC; ++ntl) {
            f32x4 cacc = {0.f, 0.f, 0.f, 0.f};
#pragma unroll
            for (int kb = 0; kb < KB; ++kb) {
                const bf16x8 b = ((const bf16x8*)buf)[(ntl * KB + kb) * 64 + lane];
                cacc = __builtin_amdgcn_mfma_f32_16x16x32_bf16(a[kb], b, cacc, 0, 0, 0);
            }
            acc[c * NTC + ntl] = cacc;
        }
    }

    // bias + row stats
    float s[4] = {0.f, 0.f, 0.f, 0.f};
    float q[4] = {0.f, 0.f, 0.f, 0.f};
#pragma unroll
    for (int nt = 0; nt < 16; ++nt) {
        const float bv = bias[nt * 16 + colbase];
#pragma unroll
        for (int rg = 0; rg < 4; ++rg) {
            const float v = acc[nt][rg] + bv;
            acc[nt][rg] = v;
            s[rg] += v;
            q[rg] += v * v;
        }
    }
#pragma unroll
    for (int off = 1; off < 16; off <<= 1) {
#pragma unroll
        for (int rg = 0; rg < 4; ++rg) {
            s[rg] += __shfl_xor(s[rg], off, 64);
            q[rg] += __shfl_xor(q[rg], off, 64);
        }
    }
    float mu[4], rsd[4];
#pragma unroll
    for (int rg = 0; rg < 4; ++rg) {
        mu[rg] = s[rg] * (1.f / 256.f);
        const float var = q[rg] * (1.f / 256.f) - mu[rg] * mu[rg];
        rsd[rg] = rsqrtf(var + LN_EPS);
    }

    const int orow0 = row0 + (lane >> 4) * 4;
    if (PROJ) {
        // proj: KB=4, 4-nt chunks of 16 KB, 4 phases; chunk 0 already issued
        // into lds[NPH&1] == lds[0] (NPH even).
#pragma unroll
        for (int pc = 0; pc < 4; ++pc) {
            __syncthreads();                   // proj chunk pc landed
            if (pc < 3)
                stage_async<4>(Wpp + (size_t)(pc + 1) * 8192, lds[(pc + 1) & 1]);
            const short* buf = lds[pc & 1];
#pragma unroll
            for (int ntl = 0; ntl < 4; ++ntl) {
                const int nt = pc * 4 + ntl;
                f32x4 pid = {0.f, 0.f, 0.f, 0.f};
#pragma unroll
                for (int kb = 0; kb < 4; ++kb) {
                    const bf16x8 b = ((const bf16x8*)buf)[(ntl * 4 + kb) * 64 + lane];
                    pid = __builtin_amdgcn_mfma_f32_16x16x32_bf16(ap[kb], b, pid, 0, 0, 0);
                }
                const int col = nt * 16 + colbase;
                const float g = gamma[col];
                const float be = beta[col];
                const float pbv = pbias[col];
#pragma unroll
                for (int rg = 0; rg < 4; ++rg) {
                    const int orow = orow0 + rg;
                    float v = (acc[nt][rg] - mu[rg]) * rsd[rg] * g + be;
                    v += pid[rg] + pbv;
                    v = fmaxf(v, 0.f);
                    if (orow < NN) {
                        if (OUT_BF16)
                            ((short*)Yv)[(size_t)orow * 256 + col] = (short)f2b(v);
                        else
                            ((float*)Yv)[(size_t)orow * 256 + col] = v;
                    }
                }
            }
        }
    } else {
#pragma unroll
        for (int nt = 0; nt < 16; ++nt) {
            const int col = nt * 16 + colbase;
            const float g = gamma[col];
            const float be = beta[col];
#pragma unroll
            for (int rg = 0; rg < 4; ++rg) {
                const int orow = orow0 + rg;
                float v = (acc[nt][rg] - mu[rg]) * rsd[rg] * g + be;
                v = fmaxf(v, 0.f);
                if (orow < NN) {
                    if (OUT_BF16)
                        ((short*)Yv)[(size_t)orow * 256 + col] = (short)f2b(v);
                    else
                        ((float*)Yv)[(size_t)orow * 256 + col] = v;
                }
            }
        }
    }
}

// ---------------------------------------------------------------------------
extern "C" void kernel_launch(void* const* d_in, const int* in_sizes, int n_in,
                              void* d_out, int out_size, void* d_ws, size_t ws_size,
                              hipStream_t stream) {
    const float* x    = (const float*)d_in[0];
    const int*   eidx = (const int*)d_in[1];
    const float* W1   = (const float*)d_in[2];
    const float* b1   = (const float*)d_in[3];
    const float* W2   = (const float*)d_in[4];
    const float* b2   = (const float*)d_in[5];
    const float* ln1g = (const float*)d_in[6];
    const float* ln1b = (const float*)d_in[7];
    const float* ln2g = (const float*)d_in[8];
    const float* ln2b = (const float*)d_in[9];
    const float* pW   = (const float*)d_in[10];
    const float* pb   = (const float*)d_in[11];

    const int* row = eidx;        // edge_index[0]
    const int* col = eidx + NE;   // edge_index[1]
    float* out = (float*)d_out;

    short* xb     = (short*)d_ws;                    // [NN,128] bf16
    short* A1     = xb + (size_t)NN * 128;           // [NN,128] bf16 (agg of x)
    short* Bb     = A1 + (size_t)NN * 128;           // [NN,256] bf16 (h)
    short* Ag     = Bb + (size_t)NN * 256;           // [NN,256] bf16 (agg of h)
    float* dinv   = (float*)(Ag + (size_t)NN * 256); // [NN]
    int*   rowptr = (int*)(dinv + NN);               // [NN+1] (+pad)
    int*   psum   = rowptr + NN + 4;                 // [256]
    int2*  pairs  = (int2*)(psum + 256);             // [NE] (src, w bits)
    short* Wp1    = (short*)(pairs + NE);            // 128*256
    short* Wp2    = Wp1 + 128 * 256;                 // 256*256
    short* Wpp    = Wp2 + 256 * 256;                 // 128*256

    const int nscan = NN + 1;
    const int nblk = (nscan + 255) / 256;

    // ---- preprocessing: fused cvt+packs, CSR build (dinv fused into scan)
    hipMemsetAsync(rowptr, 0, (NN + 4) * sizeof(int), stream);
    prep_k<<<6762, 256, 0, stream>>>(x, W1, W2, pW, xb, Wp1, Wp2, Wpp);
    count_k<<<(NE + 255) / 256, 256, 0, stream>>>(col, rowptr);
    block_sum_k<<<nblk, 256, 0, stream>>>(rowptr, psum, nscan);
    scan_apply_k<<<nblk, 256, 0, stream>>>(rowptr, psum, dinv, nscan, nblk);
    fill_k<<<(NE + 255) / 256, 256, 0, stream>>>(row, col, dinv, rowptr, pairs);
    // rowptr is now endptr

    // ---- layer 1: A1 = agg(xb); Bb = relu(LN(A1@W1 + b1))
    gather1_k<<<(NN + 3) / 4, 256, 0, stream>>>(xb, rowptr, pairs, dinv, A1);
    gemm_ln_k<128, false, true><<<(NN + 63) / 64, 256, 0, stream>>>(
        A1, Wp1, b1, ln1g, ln1b, nullptr, nullptr, nullptr, Bb);

    // ---- layer 2: Ag = agg(Bb); out = relu(LN(Ag@W2 + b2) + xb@projW + pb)
    gather2_k<<<(NN + 3) / 4, 256, 0, stream>>>(Bb, rowptr, pairs, dinv, Ag);
    gemm_ln_k<256, true, false><<<(NN + 63) / 64, 256, 0, stream>>>(
        Ag, Wp2, b2, ln2g, ln2b, xb, Wpp, pb, out);
}